// Round 8
// baseline (5578.608 us; speedup 1.0000x reference)
//
#include <hip/hip_runtime.h>
#include <hip/hip_bf16.h>

// ---------------------------------------------------------------------------
// EnhancedContextAwareDualVQ — f32-faithful, round 4 (4th resubmit; rounds
// 4-7 were broker timeouts, no signal).
// KEY FIX: d_out is FLOAT32 (reference computes f32 outputs; comparator
// bf16-quantizes the *reference* for tolerance, buffer itself is f32).
// Evidence: identical 4081.672 error across two kernel structures = my bf16
// idx_sem pairs read as packed f32 (0x457F_xxxx = 4080.x) inside chunk 1.
// Pipeline: tiled f32 vector GEMMs + fused row-wise VQ epilogue (idx/loss to
// workspace), trivial f32 gather/finalize kernels write d_out.
// ---------------------------------------------------------------------------

__device__ __forceinline__ float blockReduceSum(float v, float* sb) {
  const int tid = threadIdx.x;
  __syncthreads();
  sb[tid] = v;
  __syncthreads();
#pragma unroll
  for (int st = 128; st >= 1; st >>= 1) {
    if (tid < st) sb[tid] += sb[tid + st];
    __syncthreads();
  }
  return sb[0];
}

__device__ __forceinline__ float blockReduceMax(float v, float* sb) {
  const int tid = threadIdx.x;
  __syncthreads();
  sb[tid] = v;
  __syncthreads();
#pragma unroll
  for (int st = 128; st >= 1; st >>= 1) {
    if (tid < st) sb[tid] = fmaxf(sb[tid], sb[tid + st]);
    __syncthreads();
  }
  return sb[0];
}

// argmax with first-index tie-breaking (matches np/jnp argmax).
__device__ __forceinline__ int blockArgMax(float v, int k, float* sv, int* sk) {
  const int tid = threadIdx.x;
  __syncthreads();
  sv[tid] = v; sk[tid] = k;
  __syncthreads();
#pragma unroll
  for (int st = 128; st >= 1; st >>= 1) {
    if (tid < st) {
      float v2 = sv[tid + st]; int k2 = sk[tid + st];
      if (v2 > sv[tid] || (v2 == sv[tid] && k2 < sk[tid])) { sv[tid] = v2; sk[tid] = k2; }
    }
    __syncthreads();
  }
  return sk[0];
}

// ---------------------------------------------------------------------------
// Generic 128x128 f32 GEMM, BK=16, 256 threads, 8x8 micro-tile per thread.
// A may be column-concat of two tensors (z_r | z_i): k >= asplit reads A1.
// BT: B row-major [Ncols x Kin] (codebook), computes A @ B^T.
// EPI: 0 none, 1 +bias, 2 +bias+relu. All dims multiples of 128/16.
// ---------------------------------------------------------------------------
template <int EPI, bool BT>
__global__ __launch_bounds__(256)
void gemm128(const float* __restrict__ A0, const float* __restrict__ A1,
             int lda, int asplit,
             const float* __restrict__ B, int ldb,
             const float* __restrict__ bias,
             float* __restrict__ C, int ldc, int Kin) {
  __shared__ float As[16][136];
  __shared__ float Bs[16][136];
  const int tid = threadIdx.x;
  const int tx = tid & 15, ty = tid >> 4;
  const int m0 = blockIdx.y * 128, n0 = blockIdx.x * 128;
  float acc[8][8] = {};

  for (int kt = 0; kt < Kin; kt += 16) {
    const float* Ab = (kt < asplit) ? (A0 + (size_t)m0 * lda + kt)
                                    : (A1 + (size_t)m0 * lda + (kt - asplit));
#pragma unroll
    for (int j = tid; j < 512; j += 256) {          // A tile 128x16 -> LDS^T
      int arow = j >> 2, c4 = (j & 3) << 2;
      float4 v = *(const float4*)(Ab + (size_t)arow * lda + c4);
      As[c4 + 0][arow] = v.x; As[c4 + 1][arow] = v.y;
      As[c4 + 2][arow] = v.z; As[c4 + 3][arow] = v.w;
    }
    if constexpr (!BT) {
#pragma unroll
      for (int j = tid; j < 512; j += 256) {        // B tile 16x128 direct
        int kk = j >> 5, n4 = (j & 31) << 2;
        float4 v = *(const float4*)(B + (size_t)(kt + kk) * ldb + n0 + n4);
        *(float4*)&Bs[kk][n4] = v;
      }
    } else {
#pragma unroll
      for (int j = tid; j < 512; j += 256) {        // B^T tile: codebook rows
        int n = j >> 2, k4 = (j & 3) << 2;
        float4 v = *(const float4*)(B + (size_t)(n0 + n) * ldb + kt + k4);
        Bs[k4 + 0][n] = v.x; Bs[k4 + 1][n] = v.y;
        Bs[k4 + 2][n] = v.z; Bs[k4 + 3][n] = v.w;
      }
    }
    __syncthreads();
#pragma unroll
    for (int kk = 0; kk < 16; ++kk) {
      float a8[8], b8[8];
      *(float4*)&a8[0] = *(const float4*)&As[kk][ty * 8];
      *(float4*)&a8[4] = *(const float4*)&As[kk][ty * 8 + 4];
      *(float4*)&b8[0] = *(const float4*)&Bs[kk][tx * 8];
      *(float4*)&b8[4] = *(const float4*)&Bs[kk][tx * 8 + 4];
#pragma unroll
      for (int i = 0; i < 8; ++i)
#pragma unroll
        for (int j = 0; j < 8; ++j) acc[i][j] += a8[i] * b8[j];
    }
    __syncthreads();
  }

  float bias8[8] = {};
  if constexpr (EPI >= 1) {
#pragma unroll
    for (int j = 0; j < 8; ++j) bias8[j] = bias[n0 + tx * 8 + j];
  }
#pragma unroll
  for (int i = 0; i < 8; ++i) {
    const int row = m0 + ty * 8 + i;
    float* crow = C + (size_t)row * ldc + n0 + tx * 8;
#pragma unroll
    for (int j = 0; j < 8; j += 4) {
      float4 v;
      v.x = acc[i][j + 0] + bias8[j + 0];
      v.y = acc[i][j + 1] + bias8[j + 1];
      v.z = acc[i][j + 2] + bias8[j + 2];
      v.w = acc[i][j + 3] + bias8[j + 3];
      if constexpr (EPI == 2) {
        v.x = fmaxf(v.x, 0.f); v.y = fmaxf(v.y, 0.f);
        v.z = fmaxf(v.z, 0.f); v.w = fmaxf(v.w, 0.f);
      }
      *(float4*)(crow + j) = v;
    }
  }
}

// LayerNorm(h)*w+b then relu, in-place, row length 1024, one block per row.
__global__ __launch_bounds__(256)
void ln_affine_relu(float* __restrict__ H, const float* __restrict__ w,
                    const float* __restrict__ b) {
  const int tid = threadIdx.x;
  float* row = H + (size_t)blockIdx.x * 1024;
  __shared__ float sred[256];
  float4 x = *(const float4*)(row + tid * 4);
  float m = blockReduceSum(x.x + x.y + x.z + x.w, sred) * (1.f / 1024.f);
  float e0 = x.x - m, e1 = x.y - m, e2 = x.z - m, e3 = x.w - m;
  float v = blockReduceSum(e0 * e0 + e1 * e1 + e2 * e2 + e3 * e3, sred) * (1.f / 1024.f);
  float inv = 1.f / sqrtf(v + 1e-5f);
  float4 wv = *(const float4*)(w + tid * 4);
  float4 bv = *(const float4*)(b + tid * 4);
  float4 y;
  y.x = fmaxf(e0 * inv * wv.x + bv.x, 0.f);
  y.y = fmaxf(e1 * inv * wv.y + bv.y, 0.f);
  y.z = fmaxf(e2 * inv * wv.z + bv.z, 0.f);
  y.w = fmaxf(e3 * inv * wv.w + bv.w, 0.f);
  *(float4*)(row + tid * 4) = y;
}

// ||row||^2 for codebook rows (length 1024), one block per row.
__global__ __launch_bounds__(256)
void rownorm2(const float* __restrict__ M, float* __restrict__ out) {
  const int tid = threadIdx.x;
  const float* row = M + (size_t)blockIdx.x * 1024;
  __shared__ float sred[256];
  float4 v = *(const float4*)(row + tid * 4);
  float t = blockReduceSum(v.x * v.x + v.y * v.y + v.z * v.z + v.w * v.w, sred);
  if (tid == 0) out[blockIdx.x] = t;
}

__global__ void initk(float* cnt) {
  if (threadIdx.x < 2) cnt[threadIdx.x] = 0.f;
}

// ---------------------------------------------------------------------------
// Row-wise VQ epilogue: computes idx (ws), per-pass loss (ws), div atomics.
// NO writes to d_out. One block (256 threads) per row; K = KPT*256.
// ---------------------------------------------------------------------------
template <int KPT>
__global__ __launch_bounds__(256)
void vq_epilogue(const float* __restrict__ zr, const float* __restrict__ zi,
                 const float* __restrict__ dots, const float* __restrict__ ctxm,
                 const float* __restrict__ cb, const float* __restrict__ adj,
                 const float* __restrict__ cbn, const int* __restrict__ prev,
                 const float* __restrict__ gatep,
                 float* __restrict__ loss_out, float* __restrict__ divcnt,
                 int* __restrict__ idx_out, int row0) {
  constexpr int K = KPT * 256;
  const int tid = threadIdx.x;
  const int lr = blockIdx.x;
  const int r = row0 + lr;
  __shared__ float sred[256];
  __shared__ int sint[256];

  // ||z||^2 (thread owns 4 contiguous columns of the 1024-concat row)
  const int c = tid * 4;
  const float* zp = (c < 512) ? (zr + (size_t)r * 512 + c)
                              : (zi + (size_t)r * 512 + (c - 512));
  float4 zv = *(const float4*)zp;
  float zn = blockReduceSum(zv.x * zv.x + zv.y * zv.y + zv.z * zv.z + zv.w * zv.w, sred);

  // nd = -clip(d_sq, 0, 10000)
  float nd[KPT];
  const float* drow = dots + (size_t)lr * K;
  float s = 0.f;
#pragma unroll
  for (int t = 0; t < KPT; ++t) {
    int k = t * 256 + tid;
    float d = (zn + cbn[k]) - 2.f * drow[k];
    d = fminf(fmaxf(d, 0.f), 10000.f);
    nd[t] = -d;
    s += nd[t];
  }
  float m1 = blockReduceSum(s, sred) * (1.f / K);
  s = 0.f;
#pragma unroll
  for (int t = 0; t < KPT; ++t) { float e = nd[t] - m1; s += e * e; }
  float inv1 = 1.f / sqrtf(blockReduceSum(s, sred) * (1.f / K) + 1e-5f);

  // idx_pure = argmax(nd) (LN monotone), init from t=0 (k always valid)
  float pbv = nd[0]; int pbk = tid;
#pragma unroll
  for (int t = 1; t < KPT; ++t) {
    int k = t * 256 + tid;
    if (nd[t] > pbv) { pbv = nd[t]; pbk = k; }
  }
  if (!(pbv == pbv)) pbv = -3.4e38f;   // NaN-normalize (k stays valid)
  int idx_pure = blockArgMax(pbv, pbk, sred, sint);

  // graph bias: LN(softmax(adj[prev])) * sigmoid(gate)
  int pidx = prev[r];
  pidx = pidx < 0 ? 0 : (pidx > K - 1 ? K - 1 : pidx);
  const float* arow = adj + (size_t)pidx * K;
  float pe[KPT];
  float mx = -3.4e38f;
#pragma unroll
  for (int t = 0; t < KPT; ++t) { pe[t] = arow[t * 256 + tid]; mx = fmaxf(mx, pe[t]); }
  mx = blockReduceMax(mx, sred);
  s = 0.f;
#pragma unroll
  for (int t = 0; t < KPT; ++t) { pe[t] = expf(pe[t] - mx); s += pe[t]; }
  float ssum = blockReduceSum(s, sred);
  s = 0.f;
#pragma unroll
  for (int t = 0; t < KPT; ++t) { pe[t] = pe[t] / ssum; s += pe[t]; }
  float mp = blockReduceSum(s, sred) * (1.f / K);
  s = 0.f;
#pragma unroll
  for (int t = 0; t < KPT; ++t) { float e = pe[t] - mp; s += e * e; }
  float invp = 1.f / sqrtf(blockReduceSum(s, sred) * (1.f / K) + 1e-5f);
  float gg = 1.f / (1.f + expf(-gatep[0]));

  // context logits LN
  float cx[KPT];
  const float* crow0 = ctxm + (size_t)lr * K;
  s = 0.f;
#pragma unroll
  for (int t = 0; t < KPT; ++t) { cx[t] = crow0[t * 256 + tid]; s += cx[t]; }
  float mc = blockReduceSum(s, sred) * (1.f / K);
  s = 0.f;
#pragma unroll
  for (int t = 0; t < KPT; ++t) { float e = cx[t] - mc; s += e * e; }
  float invc = 1.f / sqrtf(blockReduceSum(s, sred) * (1.f / K) + 1e-5f);

  // total logits argmax, init from t=0
  float bv; int bk = tid;
  {
    float tot0 = ((nd[0] - m1) * inv1 + (pe[0] - mp) * invp * gg)
                 + 3.0f * ((cx[0] - mc) * invc);
    bv = tot0;
  }
#pragma unroll
  for (int t = 1; t < KPT; ++t) {
    int k = t * 256 + tid;
    float tot = ((nd[t] - m1) * inv1 + (pe[t] - mp) * invp * gg)
                + 3.0f * ((cx[t] - mc) * invc);
    if (tot > bv) { bv = tot; bk = k; }
  }
  if (!(bv == bv)) bv = -3.4e38f;      // NaN-normalize (k stays valid)
  int idx = blockArgMax(bv, bk, sred, sint);

  if (tid == 0 && idx != idx_pure) atomicAdd(divcnt, 1.0f);

  // loss from clamped gather (epilogue reads only; writes go to ws)
  int idc = idx < 0 ? 0 : (idx > K - 1 ? K - 1 : idx);
  const float* cbrow = cb + (size_t)idc * 1024;
  float4 cv = *(const float4*)(cbrow + c);
  float dx = cv.x - zv.x, dy = cv.y - zv.y, dz = cv.z - zv.z, dw = cv.w - zv.w;
  float ls = blockReduceSum(dx * dx + dy * dy + dz * dz + dw * dw, sred);
  if (tid == 0) {
    float mse = ls * (1.f / 1024.f);
    loss_out[r] = mse + 0.25f * mse;   // 1.25 * mse
    idx_out[r] = idc;
  }
}

// zq gather: out_zq[r] = f32 cb[idx[r]].
__global__ __launch_bounds__(256)
void gather_zq(const float* __restrict__ cb, const int* __restrict__ idxa,
               float* __restrict__ out_zq, int K) {
  const int r = blockIdx.x, tid = threadIdx.x;
  int idx = idxa[r];
  idx = idx < 0 ? 0 : (idx > K - 1 ? K - 1 : idx);
  const float* row = cb + (size_t)idx * 1024;
  float4 v = *(const float4*)(row + tid * 4);
  *(float4*)(out_zq + (size_t)r * 1024 + tid * 4) = v;
}

// loss/idx/div outputs (f32).
__global__ __launch_bounds__(256)
void finalize(const float* __restrict__ loss0, const float* __restrict__ loss1,
              const int* __restrict__ idxs0, const int* __restrict__ idxs1,
              const float* __restrict__ cnt,
              float* __restrict__ out_loss,
              float* __restrict__ out_idx0,
              float* __restrict__ out_idx1,
              float* __restrict__ out_div) {
  const int r = blockIdx.x * 256 + threadIdx.x;
  if (r < 16384) {
    out_loss[r] = loss0[r] + loss1[r];
    out_idx0[r] = (float)idxs0[r];
    out_idx1[r] = (float)idxs1[r];
  }
  if (r == 0)
    out_div[0] = (cnt[0] + cnt[1]) * (0.5f / 16384.f);
}

// ---------------------------------------------------------------------------

extern "C" void kernel_launch(void* const* d_in, const int* in_sizes, int n_in,
                              void* d_out, int out_size, void* d_ws, size_t ws_size,
                              hipStream_t stream) {
  const float* zfr  = (const float*)d_in[0];
  const float* zfi  = (const float*)d_in[1];
  const float* zsr  = (const float*)d_in[2];
  const float* zsi  = (const float*)d_in[3];
  const float* cbS  = (const float*)d_in[4];
  const float* cbM  = (const float*)d_in[5];
  const float* adjS = (const float*)d_in[6];
  const float* adjM = (const float*)d_in[7];
  const float* gate = (const float*)d_in[8];
  const int*  prevS = (const int*)d_in[9];
  const int*  prevM = (const int*)d_in[10];
  const float* W1[2] = {(const float*)d_in[12], (const float*)d_in[20]};
  const float* B1[2] = {(const float*)d_in[13], (const float*)d_in[21]};
  const float* LW[2] = {(const float*)d_in[14], (const float*)d_in[22]};
  const float* LB[2] = {(const float*)d_in[15], (const float*)d_in[23]};
  const float* W2[2] = {(const float*)d_in[16], (const float*)d_in[24]};
  const float* B2[2] = {(const float*)d_in[17], (const float*)d_in[25]};
  const float* W3[2] = {(const float*)d_in[18], (const float*)d_in[26]};
  const float* B3[2] = {(const float*)d_in[19], (const float*)d_in[27]};

  float* out = (float*)d_out;                       // f32 output buffer
  float* out_zq0 = out;                             // 16384*1024
  float* out_zq1 = out + (size_t)16384 * 1024;      // 16384*1024
  float* out_loss = out + (size_t)2 * 16384 * 1024; // 16384
  float* out_idx0 = out_loss + 16384;               // 16384
  float* out_idx1 = out_loss + 2 * 16384;           // 16384
  float* out_div  = out_loss + 3 * 16384;           // 1

  float* ws = (float*)d_ws;
  float* cbn0  = ws;                     // 1024
  float* cbn1  = ws + 1024;              // 4096
  float* loss0 = ws + 5120;              // 16384
  float* loss1 = ws + 21504;             // 16384
  float* cnt   = ws + 37888;             // 2 (+pad)
  int* idxs0   = (int*)(ws + 37892);     // 16384
  int* idxs1   = (int*)(ws + 54276);     // 16384
  float* bufs  = ws + 70672;             // 16B-aligned

  size_t CH = 16384;
  while ((70672ull + CH * 9728ull) * 4ull > ws_size && CH > 128) CH >>= 1;
  float* h1   = bufs;                    // CH*1024
  float* h2   = h1 + CH * 1024;          // CH*512
  float* ctx  = h2 + CH * 512;           // CH*4096 (max)
  float* dots = ctx + CH * 4096;         // CH*4096 (max)

  initk<<<1, 64, 0, stream>>>(cnt);
  rownorm2<<<1024, 256, 0, stream>>>(cbS, cbn0);
  rownorm2<<<4096, 256, 0, stream>>>(cbM, cbn1);

  const float* zR[2]   = {zfr, zsr};
  const float* zI[2]   = {zfi, zsi};
  const float* cbs[2]  = {cbS, cbM};
  const float* adjs[2] = {adjS, adjM};
  const int*  prevs[2] = {prevS, prevM};
  float* cbns[2]  = {cbn0, cbn1};
  float* losses[2] = {loss0, loss1};
  int* idxss[2]   = {idxs0, idxs1};
  const int Ks[2] = {1024, 4096};

  const unsigned chb = (unsigned)(CH / 128);
  for (int p = 0; p < 2; ++p) {
    const int K = Ks[p];
    for (int row0 = 0; row0 < 16384; row0 += (int)CH) {
      const float* a0 = zR[p] + (size_t)row0 * 512;
      const float* a1 = zI[p] + (size_t)row0 * 512;
      // h1pre = zcat @ W1 + b1
      gemm128<1, false><<<dim3(8, chb), 256, 0, stream>>>(
          a0, a1, 512, 512, W1[p], 1024, B1[p], h1, 1024, 1024);
      // h1 = relu(LN(h1pre)*lnw + lnb)
      ln_affine_relu<<<(unsigned)CH, 256, 0, stream>>>(h1, LW[p], LB[p]);
      // h2 = relu(h1 @ W2 + b2)
      gemm128<2, false><<<dim3(4, chb), 256, 0, stream>>>(
          h1, h1, 1024, 1 << 30, W2[p], 512, B2[p], h2, 512, 1024);
      // ctx = h2 @ W3 + b3
      gemm128<1, false><<<dim3((unsigned)(K / 128), chb), 256, 0, stream>>>(
          h2, h2, 512, 1 << 30, W3[p], K, B3[p], ctx, K, 512);
      // dots = zcat @ cb^T
      gemm128<0, true><<<dim3((unsigned)(K / 128), chb), 256, 0, stream>>>(
          a0, a1, 512, 512, cbs[p], 1024, nullptr, dots, K, 1024);
      if (p == 0)
        vq_epilogue<4><<<(unsigned)CH, 256, 0, stream>>>(
            zR[p], zI[p], dots, ctx, cbs[p], adjs[p], cbns[p], prevs[p], gate,
            losses[p], cnt + 0, idxss[p], row0);
      else
        vq_epilogue<16><<<(unsigned)CH, 256, 0, stream>>>(
            zR[p], zI[p], dots, ctx, cbs[p], adjs[p], cbns[p], prevs[p], gate,
            losses[p], cnt + 1, idxss[p], row0);
    }
  }

  gather_zq<<<16384, 256, 0, stream>>>(cbS, idxs0, out_zq0, 1024);
  gather_zq<<<16384, 256, 0, stream>>>(cbM, idxs1, out_zq1, 4096);
  finalize<<<64, 256, 0, stream>>>(loss0, loss1, idxs0, idxs1, cnt,
                                   out_loss, out_idx0, out_idx1, out_div);
}